// Round 1
// baseline (187.696 us; speedup 1.0000x reference)
//
#include <hip/hip_runtime.h>
#include <math.h>

// out = sum_j W[j] * (sum_n |yt[n,j]-yp[n,j]|) / (sum_n yt[n,j])
// (the 1/N of the outer mean cancels the 1/N inside col_mean)
//
// Memory-bound reduction: 167.8 MB read, ~0 write. Target ~27 us @ 6.3 TB/s.

#define RBLOCKS 2048
#define RTHREADS 256

// Each thread consumes 4 rows = 20 floats = 5 float4s per iteration.
// Column pattern across the 5 float4s is static:
//   v0: 0,1,2,3 | v1: 4,0,1,2 | v2: 3,4,0,1 | v3: 2,3,4,0 | v4: 1,2,3,4
__global__ __launch_bounds__(RTHREADS) void regress_reduce(
    const float* __restrict__ yt, const float* __restrict__ yp,
    float* __restrict__ partials, long long nrows) {
  float s[5] = {0.f, 0.f, 0.f, 0.f, 0.f};  // sum of y_true per column
  float a[5] = {0.f, 0.f, 0.f, 0.f, 0.f};  // sum of |y_true - y_pred| per column

  const long long tid = (long long)blockIdx.x * blockDim.x + threadIdx.x;
  const long long stride = (long long)gridDim.x * blockDim.x;
  const long long ngroups = nrows >> 2;  // groups of 4 rows

#define ACC(c, tv, pv) { s[c] += (tv); a[c] += fabsf((tv) - (pv)); }

  for (long long g = tid; g < ngroups; g += stride) {
    const float4* t4 = (const float4*)(yt + g * 20);  // 80B-aligned (20*4 = 5*16)
    const float4* p4 = (const float4*)(yp + g * 20);
    float4 t0 = t4[0], t1 = t4[1], t2 = t4[2], t3 = t4[3], t4v = t4[4];
    float4 p0 = p4[0], p1 = p4[1], p2 = p4[2], p3 = p4[3], p4v = p4[4];

    ACC(0, t0.x, p0.x)  ACC(1, t0.y, p0.y)  ACC(2, t0.z, p0.z)  ACC(3, t0.w, p0.w)
    ACC(4, t1.x, p1.x)  ACC(0, t1.y, p1.y)  ACC(1, t1.z, p1.z)  ACC(2, t1.w, p1.w)
    ACC(3, t2.x, p2.x)  ACC(4, t2.y, p2.y)  ACC(0, t2.z, p2.z)  ACC(1, t2.w, p2.w)
    ACC(2, t3.x, p3.x)  ACC(3, t3.y, p3.y)  ACC(4, t3.z, p3.z)  ACC(0, t3.w, p3.w)
    ACC(1, t4v.x, p4v.x) ACC(2, t4v.y, p4v.y) ACC(3, t4v.z, p4v.z) ACC(4, t4v.w, p4v.w)
  }

  // tail rows (nrows % 4) — zero for N = 4194304, kept for generality
  const long long rem_start = ngroups << 2;
  const long long rem = nrows - rem_start;
  if (tid < rem) {
    const long long r = rem_start + tid;
#pragma unroll
    for (int c = 0; c < 5; ++c) {
      float tv = yt[r * 5 + c];
      ACC(c, tv, yp[r * 5 + c])
    }
  }
#undef ACC

  // wave (64-lane) butterfly reduce of the 10 accumulators
#pragma unroll
  for (int off = 32; off > 0; off >>= 1) {
#pragma unroll
    for (int c = 0; c < 5; ++c) {
      s[c] += __shfl_down(s[c], off, 64);
      a[c] += __shfl_down(a[c], off, 64);
    }
  }

  __shared__ float lds[RTHREADS / 64][10];
  const int lane = threadIdx.x & 63;
  const int wave = threadIdx.x >> 6;
  if (lane == 0) {
#pragma unroll
    for (int c = 0; c < 5; ++c) { lds[wave][c] = s[c]; lds[wave][5 + c] = a[c]; }
  }
  __syncthreads();
  if (threadIdx.x == 0) {
#pragma unroll
    for (int v = 0; v < 10; ++v) {
      float sum = 0.f;
#pragma unroll
      for (int w = 0; w < RTHREADS / 64; ++w) sum += lds[w][v];
      partials[(long long)blockIdx.x * 10 + v] = sum;  // deterministic, no atomics
    }
  }
}

__global__ __launch_bounds__(256) void regress_finalize(
    const float* __restrict__ partials, int nblocks, float* __restrict__ out) {
  float acc[10] = {0.f, 0.f, 0.f, 0.f, 0.f, 0.f, 0.f, 0.f, 0.f, 0.f};
  for (int b = threadIdx.x; b < nblocks; b += 256) {
#pragma unroll
    for (int v = 0; v < 10; ++v) acc[v] += partials[b * 10 + v];
  }
#pragma unroll
  for (int off = 32; off > 0; off >>= 1) {
#pragma unroll
    for (int v = 0; v < 10; ++v) acc[v] += __shfl_down(acc[v], off, 64);
  }
  __shared__ float lds[4][10];
  const int lane = threadIdx.x & 63;
  const int wave = threadIdx.x >> 6;
  if (lane == 0) {
#pragma unroll
    for (int v = 0; v < 10; ++v) lds[wave][v] = acc[v];
  }
  __syncthreads();
  if (threadIdx.x == 0) {
    const float W[5] = {0.3f, 0.175f, 0.175f, 0.175f, 0.175f};
    float r = 0.f;
#pragma unroll
    for (int c = 0; c < 5; ++c) {
      float sc = lds[0][c] + lds[1][c] + lds[2][c] + lds[3][c];
      float ac = lds[0][5 + c] + lds[1][5 + c] + lds[2][5 + c] + lds[3][5 + c];
      r += W[c] * ac / sc;
    }
    *out = r;
  }
}

extern "C" void kernel_launch(void* const* d_in, const int* in_sizes, int n_in,
                              void* d_out, int out_size, void* d_ws, size_t ws_size,
                              hipStream_t stream) {
  const float* yt = (const float*)d_in[0];
  const float* yp = (const float*)d_in[1];
  const long long nrows = (long long)in_sizes[0] / 5;
  float* partials = (float*)d_ws;  // RBLOCKS * 10 floats = 80 KB

  regress_reduce<<<RBLOCKS, RTHREADS, 0, stream>>>(yt, yp, partials, nrows);
  regress_finalize<<<1, 256, 0, stream>>>(partials, RBLOCKS, (float*)d_out);
}

// Round 2
// 187.116 us; speedup vs baseline: 1.0031x; 1.0031x over previous
//
#include <hip/hip_runtime.h>
#include <math.h>

// out = sum_j W[j] * (sum_n |yt[n,j]-yp[n,j]|) / (sum_n yt[n,j])
// (the 1/N of the outer mean cancels the 1/N inside col_mean)
//
// Memory-bound: 167.8 MB read. Floor ~27 us @ 6.3 TB/s.
//
// Coalescing strategy: lane-consecutive float4 loads (16 B/lane). Column of
// component c of float4 q is (4q+c)%5. With per-thread load stride
// T = GRID*BLOCK (4T = 2 mod 5), load k has columns (c + 2k + 4*tid) mod 5:
// (c+2k)%5 is compile-time static; 4*tid is a fixed per-thread rotation,
// un-rotated once at the end through LDS.

#define GRID 2048
#define BLOCK 256
#define TTHREADS (GRID * BLOCK)  // 524288; 4*T mod 5 == 2
#define KLOADS 10                // Q = 4194304*5/4 = 5242880 = TTHREADS * 10

__global__ __launch_bounds__(BLOCK) void regress_reduce_fast(
    const float4* __restrict__ yt4, const float4* __restrict__ yp4,
    float* __restrict__ partials) {
  const int tid = blockIdx.x * BLOCK + threadIdx.x;

  // rotated-space accumulators: local index m corresponds to global column
  // (m + 4*tid) mod 5
  float s[5] = {0.f, 0.f, 0.f, 0.f, 0.f};
  float a[5] = {0.f, 0.f, 0.f, 0.f, 0.f};

#pragma unroll
  for (int k = 0; k < KLOADS; ++k) {
    const float4 tv = yt4[tid + k * TTHREADS];  // coalesced: lane stride 16 B
    const float4 pv = yp4[tid + k * TTHREADS];
    const int m0 = (2 * k + 0) % 5;  // all static after unroll
    const int m1 = (2 * k + 1) % 5;
    const int m2 = (2 * k + 2) % 5;
    const int m3 = (2 * k + 3) % 5;
    s[m0] += tv.x; a[m0] += fabsf(tv.x - pv.x);
    s[m1] += tv.y; a[m1] += fabsf(tv.y - pv.y);
    s[m2] += tv.z; a[m2] += fabsf(tv.z - pv.z);
    s[m3] += tv.w; a[m3] += fabsf(tv.w - pv.w);
  }

  // un-rotate into global column space + block reduction via LDS
  __shared__ float red[BLOCK][11];  // 10 used + 1 pad (11 is coprime w/ 32 banks)
  const int t = threadIdx.x;
  const int rr = tid % 5;  // global col g = (m - rr + 5) % 5, since 4 = -1 mod 5
#pragma unroll
  for (int m = 0; m < 5; ++m) {
    int g = m - rr; if (g < 0) g += 5;
    red[t][g] = s[m];
    red[t][5 + g] = a[m];
  }
  __syncthreads();
#pragma unroll
  for (int off = BLOCK / 2; off > 0; off >>= 1) {
    if (t < off) {
#pragma unroll
      for (int v = 0; v < 10; ++v) red[t][v] += red[t + off][v];
    }
    __syncthreads();
  }
  if (t < 10) partials[blockIdx.x * 10 + t] = red[0][t];  // deterministic
}

// generic fallback (any nrows), correctness-first
__global__ __launch_bounds__(BLOCK) void regress_reduce_generic(
    const float* __restrict__ yt, const float* __restrict__ yp,
    float* __restrict__ partials, long long nrows) {
  float s[5] = {0.f, 0.f, 0.f, 0.f, 0.f};
  float a[5] = {0.f, 0.f, 0.f, 0.f, 0.f};
  const long long tid = (long long)blockIdx.x * blockDim.x + threadIdx.x;
  const long long stride = (long long)gridDim.x * blockDim.x;
  for (long long r = tid; r < nrows; r += stride) {
#pragma unroll
    for (int c = 0; c < 5; ++c) {
      float tv = yt[r * 5 + c];
      s[c] += tv;
      a[c] += fabsf(tv - yp[r * 5 + c]);
    }
  }
  __shared__ float red[BLOCK][11];
  const int t = threadIdx.x;
#pragma unroll
  for (int c = 0; c < 5; ++c) { red[t][c] = s[c]; red[t][5 + c] = a[c]; }
  __syncthreads();
#pragma unroll
  for (int off = BLOCK / 2; off > 0; off >>= 1) {
    if (t < off) {
#pragma unroll
      for (int v = 0; v < 10; ++v) red[t][v] += red[t + off][v];
    }
    __syncthreads();
  }
  if (t < 10) partials[blockIdx.x * 10 + t] = red[0][t];
}

__global__ __launch_bounds__(256) void regress_finalize(
    const float* __restrict__ partials, int nblocks, float* __restrict__ out) {
  float acc[10] = {0.f, 0.f, 0.f, 0.f, 0.f, 0.f, 0.f, 0.f, 0.f, 0.f};
  for (int b = threadIdx.x; b < nblocks; b += 256) {
#pragma unroll
    for (int v = 0; v < 10; ++v) acc[v] += partials[b * 10 + v];
  }
#pragma unroll
  for (int off = 32; off > 0; off >>= 1) {
#pragma unroll
    for (int v = 0; v < 10; ++v) acc[v] += __shfl_down(acc[v], off, 64);
  }
  __shared__ float lds[4][10];
  const int lane = threadIdx.x & 63;
  const int wave = threadIdx.x >> 6;
  if (lane == 0) {
#pragma unroll
    for (int v = 0; v < 10; ++v) lds[wave][v] = acc[v];
  }
  __syncthreads();
  if (threadIdx.x == 0) {
    const float W[5] = {0.3f, 0.175f, 0.175f, 0.175f, 0.175f};
    float r = 0.f;
#pragma unroll
    for (int c = 0; c < 5; ++c) {
      float sc = lds[0][c] + lds[1][c] + lds[2][c] + lds[3][c];
      float ac = lds[0][5 + c] + lds[1][5 + c] + lds[2][5 + c] + lds[3][5 + c];
      r += W[c] * ac / sc;
    }
    *out = r;
  }
}

extern "C" void kernel_launch(void* const* d_in, const int* in_sizes, int n_in,
                              void* d_out, int out_size, void* d_ws, size_t ws_size,
                              hipStream_t stream) {
  const float* yt = (const float*)d_in[0];
  const float* yp = (const float*)d_in[1];
  const long long nelem = (long long)in_sizes[0];
  const long long nrows = nelem / 5;
  float* partials = (float*)d_ws;  // GRID * 10 floats = 80 KB

  if (nelem == (long long)TTHREADS * KLOADS * 4) {
    regress_reduce_fast<<<GRID, BLOCK, 0, stream>>>(
        (const float4*)yt, (const float4*)yp, partials);
  } else {
    regress_reduce_generic<<<GRID, BLOCK, 0, stream>>>(yt, yp, partials, nrows);
  }
  regress_finalize<<<1, 256, 0, stream>>>(partials, GRID, (float*)d_out);
}

// Round 3
// 183.672 us; speedup vs baseline: 1.0219x; 1.0187x over previous
//
#include <hip/hip_runtime.h>
#include <math.h>

// out = sum_j W[j] * (sum_n |yt[n,j]-yp[n,j]|) / (sum_n yt[n,j])
// (outer mean's 1/N cancels the 1/N inside col_mean)
//
// Memory-bound: 167.8 MB read. Floor ~27 us @ 6.3 TB/s.
//
// R3: attack per-wave MLP. R1/R2 both stuck at ~65us with VGPR_Count=32 —
// compiler's load window was ~2-3. Here: explicit double-buffered batches of
// 10 in-flight float4 loads + __launch_bounds__(256,4) to allow 128 VGPRs.
//
// Column math: float4 q, component c → column (4q+c)%5. q = tid + k*TTH,
// 4*TTH ≡ 1 (mod 5) → col = (4*tid + k + c) % 5. Accumulator index
// m = (k+c)%5 (static); per-thread rotation 4*tid ≡ -tid (mod 5) un-rotated
// once at the end: g = (m - tid%5 + 5) % 5.

#define GRID 1024
#define BLOCK 256
#define TTH (GRID * BLOCK)      // 262144; 4*TTH mod 5 == 1
#define KLOADS 20               // float4s per thread per array; 262144*20 = 5242880 exact
#define BATCH 5
#define NBATCH (KLOADS / BATCH) // 4

__global__ __launch_bounds__(BLOCK, 4) void regress_reduce_fast(
    const float4* __restrict__ yt4, const float4* __restrict__ yp4,
    float* __restrict__ partials) {
  const int tid = blockIdx.x * BLOCK + threadIdx.x;

  float s[5] = {0.f, 0.f, 0.f, 0.f, 0.f};
  float a[5] = {0.f, 0.f, 0.f, 0.f, 0.f};

  const float4* At = yt4 + tid;
  const float4* Ap = yp4 + tid;

  float4 t[2][BATCH], p[2][BATCH];

  // prologue: issue batch 0 (10 loads in flight)
#pragma unroll
  for (int j = 0; j < BATCH; ++j) {
    t[0][j] = At[(long long)j * TTH];
    p[0][j] = Ap[(long long)j * TTH];
  }

#pragma unroll
  for (int b = 0; b < NBATCH; ++b) {
    const int cur = b & 1, nxt = cur ^ 1;
    if (b + 1 < NBATCH) {  // issue next batch before consuming current
#pragma unroll
      for (int j = 0; j < BATCH; ++j) {
        t[nxt][j] = At[(long long)((b + 1) * BATCH + j) * TTH];
        p[nxt][j] = Ap[(long long)((b + 1) * BATCH + j) * TTH];
      }
    }
#pragma unroll
    for (int j = 0; j < BATCH; ++j) {
      const int k = b * BATCH + j;
      const int m0 = (k + 0) % 5;  // static after unroll
      const int m1 = (k + 1) % 5;
      const int m2 = (k + 2) % 5;
      const int m3 = (k + 3) % 5;
      const float4 tv = t[cur][j], pv = p[cur][j];
      s[m0] += tv.x; a[m0] += fabsf(tv.x - pv.x);
      s[m1] += tv.y; a[m1] += fabsf(tv.y - pv.y);
      s[m2] += tv.z; a[m2] += fabsf(tv.z - pv.z);
      s[m3] += tv.w; a[m3] += fabsf(tv.w - pv.w);
    }
  }

  // un-rotate into global column space + block reduction via LDS
  __shared__ float red[BLOCK][11];  // +1 pad
  const int tix = threadIdx.x;
  const int rr = tid % 5;
#pragma unroll
  for (int m = 0; m < 5; ++m) {
    int g = m - rr; if (g < 0) g += 5;
    red[tix][g] = s[m];
    red[tix][5 + g] = a[m];
  }
  __syncthreads();
#pragma unroll
  for (int off = BLOCK / 2; off > 0; off >>= 1) {
    if (tix < off) {
#pragma unroll
      for (int v = 0; v < 10; ++v) red[tix][v] += red[tix + off][v];
    }
    __syncthreads();
  }
  if (tix < 10) partials[blockIdx.x * 10 + tix] = red[0][tix];  // deterministic
}

// generic fallback (any nrows), correctness-first
__global__ __launch_bounds__(BLOCK) void regress_reduce_generic(
    const float* __restrict__ yt, const float* __restrict__ yp,
    float* __restrict__ partials, long long nrows) {
  float s[5] = {0.f, 0.f, 0.f, 0.f, 0.f};
  float a[5] = {0.f, 0.f, 0.f, 0.f, 0.f};
  const long long tid = (long long)blockIdx.x * blockDim.x + threadIdx.x;
  const long long stride = (long long)gridDim.x * blockDim.x;
  for (long long r = tid; r < nrows; r += stride) {
#pragma unroll
    for (int c = 0; c < 5; ++c) {
      float tv = yt[r * 5 + c];
      s[c] += tv;
      a[c] += fabsf(tv - yp[r * 5 + c]);
    }
  }
  __shared__ float red[BLOCK][11];
  const int t = threadIdx.x;
#pragma unroll
  for (int c = 0; c < 5; ++c) { red[t][c] = s[c]; red[t][5 + c] = a[c]; }
  __syncthreads();
#pragma unroll
  for (int off = BLOCK / 2; off > 0; off >>= 1) {
    if (t < off) {
#pragma unroll
      for (int v = 0; v < 10; ++v) red[t][v] += red[t + off][v];
    }
    __syncthreads();
  }
  if (t < 10) partials[blockIdx.x * 10 + t] = red[0][t];
}

__global__ __launch_bounds__(256) void regress_finalize(
    const float* __restrict__ partials, int nblocks, float* __restrict__ out) {
  float acc[10] = {0.f, 0.f, 0.f, 0.f, 0.f, 0.f, 0.f, 0.f, 0.f, 0.f};
  for (int b = threadIdx.x; b < nblocks; b += 256) {
#pragma unroll
    for (int v = 0; v < 10; ++v) acc[v] += partials[b * 10 + v];
  }
#pragma unroll
  for (int off = 32; off > 0; off >>= 1) {
#pragma unroll
    for (int v = 0; v < 10; ++v) acc[v] += __shfl_down(acc[v], off, 64);
  }
  __shared__ float lds[4][10];
  const int lane = threadIdx.x & 63;
  const int wave = threadIdx.x >> 6;
  if (lane == 0) {
#pragma unroll
    for (int v = 0; v < 10; ++v) lds[wave][v] = acc[v];
  }
  __syncthreads();
  if (threadIdx.x == 0) {
    const float W[5] = {0.3f, 0.175f, 0.175f, 0.175f, 0.175f};
    float r = 0.f;
#pragma unroll
    for (int c = 0; c < 5; ++c) {
      float sc = lds[0][c] + lds[1][c] + lds[2][c] + lds[3][c];
      float ac = lds[0][5 + c] + lds[1][5 + c] + lds[2][5 + c] + lds[3][5 + c];
      r += W[c] * ac / sc;
    }
    *out = r;
  }
}

extern "C" void kernel_launch(void* const* d_in, const int* in_sizes, int n_in,
                              void* d_out, int out_size, void* d_ws, size_t ws_size,
                              hipStream_t stream) {
  const float* yt = (const float*)d_in[0];
  const float* yp = (const float*)d_in[1];
  const long long nelem = (long long)in_sizes[0];
  const long long nrows = nelem / 5;
  float* partials = (float*)d_ws;  // GRID * 10 floats = 40 KB

  if (nelem == (long long)TTH * KLOADS * 4) {
    regress_reduce_fast<<<GRID, BLOCK, 0, stream>>>(
        (const float4*)yt, (const float4*)yp, partials);
  } else {
    regress_reduce_generic<<<GRID, BLOCK, 0, stream>>>(yt, yp, partials, nrows);
  }
  regress_finalize<<<1, 256, 0, stream>>>(partials, GRID, (float*)d_out);
}